// Round 9
// baseline (140.794 us; speedup 1.0000x reference)
//
#include <hip/hip_runtime.h>
#include <hip/hip_bf16.h>
#include <hip/hip_fp16.h>

// ARAPLoss: out[b] = mean_e | ||x[b,dst]-x[b,src]||^2 - ||dx[b,dst]-dx[b,src]||^2 |
// B=8, NV=100000, E ~ 1.19M directed dedup edges (sorted by src, symmetric).
//
// History: R1 345us (L2 thrash). R2 66us (pack+batch/XCD). R3 97us (unpacked).
// R4 220us prep (cross-XCD same-line atomics: never). R5 64us (f16+s<d pred).
// R6 58us (int4 idx, 4 edges/iter). R8 ~55us (shared walk, 96B records).
// FALSIFIED: per-lane-request count (R2 vs R5: 4x, no change), iteration count
// (R6: 4x, -10%), paper line-touches (R8: 8x, small). INVARIANT: FETCH 44-54MB,
// dur ~= FETCH / 800GB/s. Harness overhead (~70us: 268MB ws poison at 6TB/s +
// input restore) is untouchable.
// R9 (discriminating experiment): lane-cooperative 128B-aligned records
// (8 batches x 16B f16). 8 lanes per edge, one batch per lane -> per endpoint
// ONE dwordx4/lane, per active edge 2 gather instrs / 4 distinct lines (vs
// 12 instrs / ~12 lines in R8). Same FETCH bytes. If TCP-line model right:
// main ~15-20us. If L2-fill model right: unchanged ~50us -> wall identified.

#define NBATCH 8
#define NVERT 100000
#define MAIN_BLOCKS 4096

union RecU {
    float4 f4;
    __half h[8];
};

// ---- prep: rec_f4[v*8 + b] = f16 {x0,x1,x2,dx0,dx1,dx2,0,0}; 128B/vertex ----
__global__ __launch_bounds__(256) void arap_pack128_kernel(
    const float* __restrict__ dx, const float* __restrict__ x,
    float4* __restrict__ recs)
{
    const int t = blockIdx.x * blockDim.x + threadIdx.x;
    if (t >= NBATCH * NVERT) return;
    const int b = t / NVERT;
    const int v = t - b * NVERT;
    const size_t s = (size_t)b * NVERT * 3 + (size_t)v * 3;
    RecU u;
    u.h[0] = __float2half_rn(x[s]);
    u.h[1] = __float2half_rn(x[s + 1]);
    u.h[2] = __float2half_rn(x[s + 2]);
    u.h[3] = __float2half_rn(dx[s]);
    u.h[4] = __float2half_rn(dx[s + 1]);
    u.h[5] = __float2half_rn(dx[s + 2]);
    u.h[6] = __half(0.0f);
    u.h[7] = __half(0.0f);
    recs[(size_t)v * NBATCH + b] = u.f4;
}

__device__ __forceinline__ float edge_term(const RecU& a, const RecU& c) {
    const float ex0 = __half2float(c.h[0]) - __half2float(a.h[0]);
    const float ex1 = __half2float(c.h[1]) - __half2float(a.h[1]);
    const float ex2 = __half2float(c.h[2]) - __half2float(a.h[2]);
    const float ed0 = __half2float(c.h[3]) - __half2float(a.h[3]);
    const float ed1 = __half2float(c.h[4]) - __half2float(a.h[4]);
    const float ed2 = __half2float(c.h[5]) - __half2float(a.h[5]);
    return fabsf(ex0 * ex0 + ex1 * ex1 + ex2 * ex2
                 - (ed0 * ed0 + ed1 * ed1 + ed2 * ed2));
}

// ---- main: 8 lanes per edge (lane&7 = batch); one dwordx4 per endpoint ----
__global__ __launch_bounds__(256) void arap_lanecoop_kernel(
    const float4* __restrict__ recs,
    const int* __restrict__ src, const int* __restrict__ dst,
    float* __restrict__ partial, int E)
{
    const int t = blockIdx.x * blockDim.x + threadIdx.x;
    const int sub = threadIdx.x & 7;                 // batch handled by this lane
    const int gstride = (gridDim.x * blockDim.x) >> 3;

    float acc = 0.0f;
    for (int e = t >> 3; e < E; e += gstride) {
        const int s = __builtin_nontemporal_load(src + e);  // 8-way broadcast
        const int d = __builtin_nontemporal_load(dst + e);
        if (s < d) {  // symmetric edge set: count each undirected edge once (x2 in scale)
            RecU a, c;
            a.f4 = recs[(size_t)s * NBATCH + sub];
            c.f4 = recs[(size_t)d * NBATCH + sub];
            acc += edge_term(a, c);
        }
    }

    // sum lanes with the same (lane&7): lanes 0..7 end up with batch sums
    acc += __shfl_down(acc, 32, 64);
    acc += __shfl_down(acc, 16, 64);
    acc += __shfl_down(acc, 8, 64);

    __shared__ float red[4][NBATCH];
    const int wave = threadIdx.x >> 6;
    const int lane = threadIdx.x & 63;
    if (lane < NBATCH) red[wave][lane] = acc;
    __syncthreads();
    if (threadIdx.x < NBATCH) {  // plain stores — no atomics (R4 lesson)
        const int b = threadIdx.x;
        partial[(size_t)blockIdx.x * NBATCH + b] =
            red[0][b] + red[1][b] + red[2][b] + red[3][b];
    }
}

// ---- reducer: 1 block; sum MAIN_BLOCKS x 8 partials, scale, write out ----
__global__ __launch_bounds__(256) void arap_reduce_kernel(
    const float* __restrict__ partial, float* __restrict__ out, float scale)
{
    const int t = threadIdx.x;
    const int b = t >> 5;          // 8 batches x 32 threads
    const int k = t & 31;
    float v = 0.0f;
    for (int i = k; i < MAIN_BLOCKS; i += 32)
        v += partial[(size_t)i * NBATCH + b];
#pragma unroll
    for (int off = 16; off > 0; off >>= 1)
        v += __shfl_down(v, off, 32);
    if (k == 0) out[b] = v * scale;
}

// ---- fallback (tiny ws): R1 kernel, self-contained ----
__global__ __launch_bounds__(256) void arap_edge_kernel(
    const float* __restrict__ dx, const float* __restrict__ x,
    const int* __restrict__ src, const int* __restrict__ dst,
    float* __restrict__ out, int E, float invE)
{
    float acc[NBATCH];
#pragma unroll
    for (int b = 0; b < NBATCH; ++b) acc[b] = 0.0f;
    const int stride = gridDim.x * blockDim.x;
    const size_t bstride = (size_t)NVERT * 3;
    for (int e = blockIdx.x * blockDim.x + threadIdx.x; e < E; e += stride) {
        const int s = src[e] * 3;
        const int d = dst[e] * 3;
#pragma unroll
        for (int b = 0; b < NBATCH; ++b) {
            const float* __restrict__ xb  = x  + b * bstride;
            const float* __restrict__ dxb = dx + b * bstride;
            float ex0 = xb[d] - xb[s], ex1 = xb[d+1] - xb[s+1], ex2 = xb[d+2] - xb[s+2];
            float ed0 = dxb[d] - dxb[s], ed1 = dxb[d+1] - dxb[s+1], ed2 = dxb[d+2] - dxb[s+2];
            acc[b] += fabsf(ex0*ex0 + ex1*ex1 + ex2*ex2 - (ed0*ed0 + ed1*ed1 + ed2*ed2));
        }
    }
#pragma unroll
    for (int b = 0; b < NBATCH; ++b)
#pragma unroll
        for (int off = 32; off > 0; off >>= 1)
            acc[b] += __shfl_down(acc[b], off, 64);
    __shared__ float red[4][NBATCH];
    const int wave = threadIdx.x >> 6;
    const int lane = threadIdx.x & 63;
    if (lane == 0)
#pragma unroll
        for (int b = 0; b < NBATCH; ++b) red[wave][b] = acc[b];
    __syncthreads();
    if (threadIdx.x == 0)
#pragma unroll
        for (int b = 0; b < NBATCH; ++b)
            atomicAdd(&out[b], (red[0][b] + red[1][b] + red[2][b] + red[3][b]) * invE);
}

extern "C" void kernel_launch(void* const* d_in, const int* in_sizes, int n_in,
                              void* d_out, int out_size, void* d_ws, size_t ws_size,
                              hipStream_t stream) {
    const float* dx = (const float*)d_in[0];
    const float* x  = (const float*)d_in[1];
    const int* edge_src = (const int*)d_in[2];
    const int* edge_dst = (const int*)d_in[3];
    float* out = (float*)d_out;

    const int E = in_sizes[2];
    const float scale2 = 2.0f / (float)E;

    const size_t rec_bytes = (size_t)NVERT * NBATCH * sizeof(float4);   // 12.8 MB
    const size_t part_off  = (rec_bytes + 255) & ~(size_t)255;
    const size_t need = part_off + (size_t)MAIN_BLOCKS * NBATCH * sizeof(float);

    if (ws_size >= need) {
        float4* recs = (float4*)d_ws;
        float* partial = (float*)((char*)d_ws + part_off);

        arap_pack128_kernel<<<(NBATCH * NVERT + 255) / 256, 256, 0, stream>>>(dx, x, recs);
        arap_lanecoop_kernel<<<MAIN_BLOCKS, 256, 0, stream>>>(recs, edge_src, edge_dst,
                                                              partial, E);
        arap_reduce_kernel<<<1, 256, 0, stream>>>(partial, out, scale2);
    } else {
        (void)hipMemsetAsync(d_out, 0, NBATCH * sizeof(float), stream);
        int blocks = (E + 255) / 256;
        if (blocks > 2048) blocks = 2048;
        arap_edge_kernel<<<blocks, 256, 0, stream>>>(dx, x, edge_src, edge_dst,
                                                     out, E, 1.0f / (float)E);
    }
}

// Round 10
// 125.228 us; speedup vs baseline: 1.1243x; 1.1243x over previous
//
#include <hip/hip_runtime.h>
#include <hip/hip_bf16.h>
#include <hip/hip_fp16.h>

// ARAPLoss: out[b] = mean_e | ||x[b,dst]-x[b,src]||^2 - ||dx[b,dst]-dx[b,src]||^2 |
// B=8, NV=100000, E ~ 1.19M directed dedup edges (sorted by src, symmetric).
//
// History: R1 345us. R2 66us (pack+batch/XCD). R5 64us (f16 recs + s<d pred).
// R6/R7 58us (int4 idx, 4 edges/iter). R8/R9 shared-walk & lane-coop: neutral.
// FALSIFIED: gather-instr count, iteration count, line-touches/instr, index
// volume. STANDING MODEL: dur ~= FETCH / 0.8TB/s — random 64B line-fill rate
// below L2. The harness's 268MB ws poison (>= 256MB LLC) flushes LLC before
// EVERY launch -> all table lines are compulsory misses via the slow random
// path. R7 FETCH 43.8MB = 22MB compulsory + ~21MB L2 re-fetch (9.5MB index
// stream evicts the 1.6MB slice from 4MiB L2).
// R10: R7 structure + WARM PHASE: each block sequentially preloads its share
// of its batch's record slice (coalesced, stream-BW fill of L2) before the
// edge loop; warm values consumed via runtime-0 multiplier. Plain-store
// partials + reducer instead of 2048 atomics.

#define NBATCH 8
#define NVERT 100000
#define MAIN_BLOCKS 2048
#define BLOCKS_PER_BATCH (MAIN_BLOCKS / NBATCH)   // 256

typedef int iv4 __attribute__((ext_vector_type(4)));

union RecU {
    float4 f4;
    __half h[8];
};

// ---- prep: rec[b*NVERT+v] = f16 {x0,x1,x2,dx0,dx1,dx2,0,0} (16B) ----
__global__ __launch_bounds__(256) void arap_pack16_kernel(
    const float* __restrict__ dx, const float* __restrict__ x,
    float4* __restrict__ recs)
{
    const int t = blockIdx.x * blockDim.x + threadIdx.x;
    if (t >= NBATCH * NVERT) return;
    const int b = t / NVERT;
    const int v = t - b * NVERT;
    const size_t s = (size_t)b * NVERT * 3 + (size_t)v * 3;
    RecU u;
    u.h[0] = __float2half_rn(x[s]);
    u.h[1] = __float2half_rn(x[s + 1]);
    u.h[2] = __float2half_rn(x[s + 2]);
    u.h[3] = __float2half_rn(dx[s]);
    u.h[4] = __float2half_rn(dx[s + 1]);
    u.h[5] = __float2half_rn(dx[s + 2]);
    u.h[6] = __half(0.0f);
    u.h[7] = __half(0.0f);
    recs[t] = u.f4;
}

__device__ __forceinline__ float edge_term(const RecU& a, const RecU& c) {
    const float ex0 = __half2float(c.h[0]) - __half2float(a.h[0]);
    const float ex1 = __half2float(c.h[1]) - __half2float(a.h[1]);
    const float ex2 = __half2float(c.h[2]) - __half2float(a.h[2]);
    const float ed0 = __half2float(c.h[3]) - __half2float(a.h[3]);
    const float ed1 = __half2float(c.h[4]) - __half2float(a.h[4]);
    const float ed2 = __half2float(c.h[5]) - __half2float(a.h[5]);
    return fabsf(ex0 * ex0 + ex1 * ex1 + ex2 * ex2
                 - (ed0 * ed0 + ed1 * ed1 + ed2 * ed2));
}

// ---- main: warm L2 with slice sequentially, then gather (R7 structure) ----
__global__ __launch_bounds__(256) void arap_main_warm_kernel(
    const float4* __restrict__ recs,
    const int* __restrict__ src, const int* __restrict__ dst,
    float* __restrict__ partial, int E, float warm_scale /* 0.0f at runtime */)
{
    const int b = blockIdx.x & 7;               // batch == XCD affinity
    const int chunk = blockIdx.x >> 3;          // 0..255 within batch
    const int tpb = BLOCKS_PER_BATCH * blockDim.x;
    const int tid = chunk * blockDim.x + threadIdx.x;
    const float4* __restrict__ rb = recs + (size_t)b * NVERT;

    float acc = 0.0f;

    // --- warm: sequential, coalesced fill of this batch's 1.6MB slice into L2.
    // Block `chunk` covers recs [chunk*391, ...); consumed via warm_scale=0.
    {
        const int per_block = (NVERT + BLOCKS_PER_BATCH - 1) / BLOCKS_PER_BATCH; // 391
        const int base = chunk * per_block;
        float wsum = 0.0f;
        for (int i = base + threadIdx.x; i < base + per_block && i < NVERT; i += 256) {
            const float4 w = rb[i];
            wsum += w.x + w.z;                  // cheap consume
        }
        acc += wsum * warm_scale;               // runtime 0 — not DCE-able
    }

    // --- edge loop: int4 index loads, 4 edges/thread/iter, masked gathers
    const iv4* __restrict__ src4 = (const iv4*)src;
    const iv4* __restrict__ dst4 = (const iv4*)dst;
    const int nquad = E >> 2;

    for (int q = tid; q < nquad; q += tpb) {
        const iv4 s4 = __builtin_nontemporal_load(src4 + q);
        const iv4 d4 = __builtin_nontemporal_load(dst4 + q);
        const bool p0 = s4.x < d4.x;
        const bool p1 = s4.y < d4.y;
        const bool p2 = s4.z < d4.z;
        const bool p3 = s4.w < d4.w;
        RecU a0, c0, a1, c1, a2, c2, a3, c3;
        a0.f4 = c0.f4 = a1.f4 = c1.f4 = make_float4(0.f, 0.f, 0.f, 0.f);
        a2.f4 = c2.f4 = a3.f4 = c3.f4 = make_float4(0.f, 0.f, 0.f, 0.f);
        if (p0) { a0.f4 = rb[s4.x]; c0.f4 = rb[d4.x]; }
        if (p1) { a1.f4 = rb[s4.y]; c1.f4 = rb[d4.y]; }
        if (p2) { a2.f4 = rb[s4.z]; c2.f4 = rb[d4.z]; }
        if (p3) { a3.f4 = rb[s4.w]; c3.f4 = rb[d4.w]; }
        acc += edge_term(a0, c0);
        acc += edge_term(a1, c1);
        acc += edge_term(a2, c2);
        acc += edge_term(a3, c3);
    }

    // tail edges
    const int rem = E - (nquad << 2);
    if (tid < rem) {
        const int e = (nquad << 2) + tid;
        const int s = src[e];
        const int d = dst[e];
        if (s < d) {
            RecU a, c;
            a.f4 = rb[s];
            c.f4 = rb[d];
            acc += edge_term(a, c);
        }
    }

    // block reduction -> plain store (no atomics)
#pragma unroll
    for (int off = 32; off > 0; off >>= 1)
        acc += __shfl_down(acc, off, 64);

    __shared__ float red[4];
    const int wave = threadIdx.x >> 6;
    const int lane = threadIdx.x & 63;
    if (lane == 0) red[wave] = acc;
    __syncthreads();
    if (threadIdx.x == 0)
        partial[blockIdx.x] = red[0] + red[1] + red[2] + red[3];
}

// ---- reducer: partial[blk] belongs to batch blk&7; sum, scale, write ----
__global__ __launch_bounds__(256) void arap_reduce_kernel(
    const float* __restrict__ partial, float* __restrict__ out, float scale)
{
    const int t = threadIdx.x;
    const int b = t >> 5;          // 8 batches x 32 threads
    const int k = t & 31;
    float v = 0.0f;
    for (int i = k; i < BLOCKS_PER_BATCH; i += 32)
        v += partial[i * NBATCH + b];   // partial[(i*8)+b] == block i*8+b, batch b
#pragma unroll
    for (int off = 16; off > 0; off >>= 1)
        v += __shfl_down(v, off, 32);
    if (k == 0) out[b] = v * scale;
}

// ---- fallback (tiny ws): R1 kernel, self-contained ----
__global__ __launch_bounds__(256) void arap_edge_kernel(
    const float* __restrict__ dx, const float* __restrict__ x,
    const int* __restrict__ src, const int* __restrict__ dst,
    float* __restrict__ out, int E, float invE)
{
    float acc[NBATCH];
#pragma unroll
    for (int b = 0; b < NBATCH; ++b) acc[b] = 0.0f;
    const int stride = gridDim.x * blockDim.x;
    const size_t bstride = (size_t)NVERT * 3;
    for (int e = blockIdx.x * blockDim.x + threadIdx.x; e < E; e += stride) {
        const int s = src[e] * 3;
        const int d = dst[e] * 3;
#pragma unroll
        for (int b = 0; b < NBATCH; ++b) {
            const float* __restrict__ xb  = x  + b * bstride;
            const float* __restrict__ dxb = dx + b * bstride;
            float ex0 = xb[d] - xb[s], ex1 = xb[d+1] - xb[s+1], ex2 = xb[d+2] - xb[s+2];
            float ed0 = dxb[d] - dxb[s], ed1 = dxb[d+1] - dxb[s+1], ed2 = dxb[d+2] - dxb[s+2];
            acc[b] += fabsf(ex0*ex0 + ex1*ex1 + ex2*ex2 - (ed0*ed0 + ed1*ed1 + ed2*ed2));
        }
    }
#pragma unroll
    for (int b = 0; b < NBATCH; ++b)
#pragma unroll
        for (int off = 32; off > 0; off >>= 1)
            acc[b] += __shfl_down(acc[b], off, 64);
    __shared__ float red[4][NBATCH];
    const int wave = threadIdx.x >> 6;
    const int lane = threadIdx.x & 63;
    if (lane == 0)
#pragma unroll
        for (int b = 0; b < NBATCH; ++b) red[wave][b] = acc[b];
    __syncthreads();
    if (threadIdx.x == 0)
#pragma unroll
        for (int b = 0; b < NBATCH; ++b)
            atomicAdd(&out[b], (red[0][b] + red[1][b] + red[2][b] + red[3][b]) * invE);
}

extern "C" void kernel_launch(void* const* d_in, const int* in_sizes, int n_in,
                              void* d_out, int out_size, void* d_ws, size_t ws_size,
                              hipStream_t stream) {
    const float* dx = (const float*)d_in[0];
    const float* x  = (const float*)d_in[1];
    const int* edge_src = (const int*)d_in[2];
    const int* edge_dst = (const int*)d_in[3];
    float* out = (float*)d_out;

    const int E = in_sizes[2];
    const float scale2 = 2.0f / (float)E;

    const size_t rec_bytes = (size_t)NBATCH * NVERT * sizeof(float4);   // 12.8 MB
    const size_t part_off  = (rec_bytes + 255) & ~(size_t)255;
    const size_t need = part_off + (size_t)MAIN_BLOCKS * sizeof(float);

    if (ws_size >= need) {
        float4* recs = (float4*)d_ws;
        float* partial = (float*)((char*)d_ws + part_off);

        arap_pack16_kernel<<<(NBATCH * NVERT + 255) / 256, 256, 0, stream>>>(dx, x, recs);
        arap_main_warm_kernel<<<MAIN_BLOCKS, 256, 0, stream>>>(
            recs, edge_src, edge_dst, partial, E, 0.0f);
        arap_reduce_kernel<<<1, 256, 0, stream>>>(partial, out, scale2);
    } else {
        (void)hipMemsetAsync(d_out, 0, NBATCH * sizeof(float), stream);
        int blocks = (E + 255) / 256;
        if (blocks > 2048) blocks = 2048;
        arap_edge_kernel<<<blocks, 256, 0, stream>>>(dx, x, edge_src, edge_dst,
                                                     out, E, 1.0f / (float)E);
    }
}